// Round 1
// baseline (674.741 us; speedup 1.0000x reference)
//
#include <hip/hip_runtime.h>

// GCN: h = relu( D^-1/2 (A+I) D^-1/2 (x@W1) + b1 ); z = h@W2 + b2
// out = [h (N*3) | z (N*7)] float32.
//
// Normalization factored:  agg[d] = dinv[d] * ( sum_{s->d} h[s]*dinv[s]  +  h[d]*dinv[d] )
// so the edge pass needs only dinv[src], and the self-loop folds into the epilogue.

// ---------- runtime dtype detection for edge_index (int64 vs int32) ----------
// Values are in [0, 100000) < 2^31. If the buffer is little-endian int64, every
// odd 32-bit word is zero. If int32, odd words are random node ids (P(all zero)
// ~ 1e-640). Deterministic, graph-safe.
__global__ void k_detect(const unsigned int* __restrict__ ei, int* __restrict__ flag) {
    if (blockIdx.x == 0 && threadIdx.x == 0) {
        int is64 = 1;
        for (int i = 1; i < 512; i += 2) {
            if (ei[i] != 0u) { is64 = 0; break; }
        }
        *flag = is64;
    }
}

// ---------- h_pre = x @ W1  (one wave per node; 64 lanes x float4 = 256 feats) ----
__global__ __launch_bounds__(256) void k_xw1(const float* __restrict__ x,
                                             const float* __restrict__ W1,
                                             float* __restrict__ hpre,
                                             float* __restrict__ deg,
                                             int N) {
    const int lane = threadIdx.x & 63;
    // per-lane weight slice W1[(lane*4+k)][c], fixed across nodes -> registers
    float w[4][3];
#pragma unroll
    for (int k = 0; k < 4; ++k)
#pragma unroll
        for (int c = 0; c < 3; ++c)
            w[k][c] = W1[(lane * 4 + k) * 3 + c];

    const int gtid    = blockIdx.x * blockDim.x + threadIdx.x;
    const int nthread = gridDim.x * blockDim.x;
    // fused: init deg with the self-loop count (1.0)
    for (int i = gtid; i < N; i += nthread) deg[i] = 1.0f;

    const int wave   = gtid >> 6;
    const int nwaves = nthread >> 6;
    for (int node = wave; node < N; node += nwaves) {
        const float4 v = *reinterpret_cast<const float4*>(x + (size_t)node * 256 + lane * 4);
        float s0 = v.x * w[0][0] + v.y * w[1][0] + v.z * w[2][0] + v.w * w[3][0];
        float s1 = v.x * w[0][1] + v.y * w[1][1] + v.z * w[2][1] + v.w * w[3][1];
        float s2 = v.x * w[0][2] + v.y * w[1][2] + v.z * w[2][2] + v.w * w[3][2];
#pragma unroll
        for (int off = 32; off > 0; off >>= 1) {
            s0 += __shfl_xor(s0, off, 64);
            s1 += __shfl_xor(s1, off, 64);
            s2 += __shfl_xor(s2, off, 64);
        }
        if (lane == 0) {
            hpre[(size_t)node * 3 + 0] = s0;
            hpre[(size_t)node * 3 + 1] = s1;
            hpre[(size_t)node * 3 + 2] = s2;
        }
    }
}

// ---------- deg[dst] += 1 over edges ----------
__global__ __launch_bounds__(256) void k_deg(const unsigned int* __restrict__ ei,
                                             const int* __restrict__ flag,
                                             float* __restrict__ deg, int E) {
    const int e = blockIdx.x * blockDim.x + threadIdx.x;
    if (e >= E) return;
    unsigned d;
    if (*flag) d = (unsigned)((const unsigned long long*)ei)[(size_t)E + e];
    else       d = ei[(size_t)E + e];
    atomicAdd(&deg[d], 1.0f);
}

// ---------- deg -> dinv; zero the edge-accumulator u ----------
__global__ __launch_bounds__(256) void k_dinv(float* __restrict__ deg,
                                              float* __restrict__ u, int N) {
    const int i = blockIdx.x * blockDim.x + threadIdx.x;
    if (i >= N) return;
    const float r = rsqrtf(deg[i]);  // deg >= 1 (self-loop), no zero case
    deg[i] = r;                      // deg becomes dinv in place
    u[3 * i + 0] = 0.0f;
    u[3 * i + 1] = 0.0f;
    u[3 * i + 2] = 0.0f;
}

// ---------- u[dst] += h_pre[src] * dinv[src] over edges ----------
__global__ __launch_bounds__(256) void k_edge(const unsigned int* __restrict__ ei,
                                              const int* __restrict__ flag,
                                              const float* __restrict__ dinv,
                                              const float* __restrict__ hpre,
                                              float* __restrict__ u, int E) {
    const int e = blockIdx.x * blockDim.x + threadIdx.x;
    if (e >= E) return;
    unsigned s, d;
    if (*flag) {
        const unsigned long long* e64 = (const unsigned long long*)ei;
        s = (unsigned)e64[e];
        d = (unsigned)e64[(size_t)E + e];
    } else {
        s = ei[e];
        d = ei[(size_t)E + e];
    }
    const float ns = dinv[s];
    atomicAdd(&u[3 * d + 0], hpre[3 * s + 0] * ns);
    atomicAdd(&u[3 * d + 1], hpre[3 * s + 1] * ns);
    atomicAdd(&u[3 * d + 2], hpre[3 * s + 2] * ns);
}

// ---------- epilogue: agg = dinv*(u + h*dinv); h = relu(agg+b1); z = h@W2+b2 ----
__global__ __launch_bounds__(256) void k_final(const float* __restrict__ u,
                                               const float* __restrict__ hpre,
                                               const float* __restrict__ dinv,
                                               const float* __restrict__ b1,
                                               const float* __restrict__ W2,
                                               const float* __restrict__ b2,
                                               float* __restrict__ out, int N) {
    const int i = blockIdx.x * blockDim.x + threadIdx.x;
    if (i >= N) return;
    const float r = dinv[i];
    float h[3];
#pragma unroll
    for (int c = 0; c < 3; ++c) {
        const float agg = r * (u[3 * i + c] + hpre[3 * i + c] * r);
        h[c] = fmaxf(agg + b1[c], 0.0f);
        out[3 * (size_t)i + c] = h[c];
    }
    float* z = out + (size_t)3 * N;
#pragma unroll
    for (int c = 0; c < 7; ++c) {
        z[7 * (size_t)i + c] = h[0] * W2[c] + h[1] * W2[7 + c] + h[2] * W2[14 + c] + b2[c];
    }
}

extern "C" void kernel_launch(void* const* d_in, const int* in_sizes, int n_in,
                              void* d_out, int out_size, void* d_ws, size_t ws_size,
                              hipStream_t stream) {
    const float*        x   = (const float*)d_in[0];
    const unsigned int* ei  = (const unsigned int*)d_in[1];
    const float*        W1  = (const float*)d_in[2];
    const float*        b1  = (const float*)d_in[3];
    const float*        W2  = (const float*)d_in[4];
    const float*        b2  = (const float*)d_in[5];
    float*              out = (float*)d_out;

    const int N = in_sizes[0] / 256;   // 100000
    const int E = in_sizes[1] / 2;     // 3200000

    // workspace layout (floats), 256B-aligned chunks
    char*  ws   = (char*)d_ws;
    int*   flag = (int*)ws;
    float* hpre = (float*)(ws + 256);                 // N*3
    float* deg  = hpre + (((size_t)3 * N + 63) & ~63ull); // N (becomes dinv)
    float* u    = deg  + (((size_t)N + 63) & ~63ull);     // N*3

    k_detect<<<1, 64, 0, stream>>>(ei, flag);
    k_xw1  <<<4096, 256, 0, stream>>>(x, W1, hpre, deg, N);
    k_deg  <<<(E + 255) / 256, 256, 0, stream>>>(ei, flag, deg, E);
    k_dinv <<<(N + 255) / 256, 256, 0, stream>>>(deg, u, N);
    k_edge <<<(E + 255) / 256, 256, 0, stream>>>(ei, flag, deg /*=dinv*/, hpre, u, E);
    k_final<<<(N + 255) / 256, 256, 0, stream>>>(u, hpre, deg /*=dinv*/, b1, W2, b2, out, N);
}

// Round 3
// 667.166 us; speedup vs baseline: 1.0114x; 1.0114x over previous
//
#include <hip/hip_runtime.h>
#include <stdint.h>

// GCN: h = relu( D^-1/2 (A+I) D^-1/2 (x@W1) + b1 ); z = h@W2 + b2
// out = [h (N*3) | z (N*7)] float32.
//
// Key idea this round: per-XCD accumulator replicas + L2-local atomics.
// Agent-scope atomicAdd on gfx950 bypasses the per-XCD L2 (non-coherent) and
// executes memory-side (300 MB of RMW traffic in round 1). Raw
// global_atomic_add_f32 with no sc bits executes at the LOCAL XCD's TCC;
// with one replica per XCD (indexed by HW_REG_XCC_ID) atomicity only needs to
// hold within the XCD. End-of-kernel release flushes L2 -> reducer sees all.
// (gfx950 has NO global_atomic_pk_add_f32 — scalar f32 atomics only.)

#define NXCD 8

__device__ __forceinline__ unsigned xcd_id() {
    unsigned x;
    asm("s_getreg_b32 %0, hwreg(HW_REG_XCC_ID)" : "=s"(x));
    return x & (NXCD - 1);
}
// L2-local (no sc bits) float atomic add
__device__ __forceinline__ void l2_fadd(float* p, float v) {
    asm volatile("global_atomic_add_f32 %0, %1, off"
                 :: "v"((unsigned long long)(uintptr_t)p), "v"(v)
                 : "memory");
}

// ---------- runtime dtype detection for edge_index (int64 vs int32) ----------
__global__ void k_detect(const unsigned int* __restrict__ ei, int* __restrict__ flag) {
    if (blockIdx.x == 0 && threadIdx.x == 0) {
        int is64 = 1;
        for (int i = 1; i < 512; i += 2) {
            if (ei[i] != 0u) { is64 = 0; break; }
        }
        *flag = is64;
    }
}

// ---------- h_pre = x @ W1 (stride-4 padded), fused zero of replicas ----------
__global__ __launch_bounds__(256) void k_xw1(const float* __restrict__ x,
                                             const float* __restrict__ W1,
                                             float* __restrict__ hpre4,
                                             float* __restrict__ zptr,
                                             int nzero4, int N) {
    const int gtid    = blockIdx.x * 256 + threadIdx.x;
    const int nthread = gridDim.x * 256;
    for (int i = gtid; i < nzero4; i += nthread)
        reinterpret_cast<float4*>(zptr)[i] = make_float4(0.f, 0.f, 0.f, 0.f);

    const int lane = threadIdx.x & 63;
    float w[4][3];
#pragma unroll
    for (int k = 0; k < 4; ++k)
#pragma unroll
        for (int c = 0; c < 3; ++c)
            w[k][c] = W1[(lane * 4 + k) * 3 + c];

    const int wave   = gtid >> 6;
    const int nwaves = nthread >> 6;
    for (int node = wave; node < N; node += nwaves) {
        const float4 v = *reinterpret_cast<const float4*>(x + (size_t)node * 256 + lane * 4);
        float s0 = v.x * w[0][0] + v.y * w[1][0] + v.z * w[2][0] + v.w * w[3][0];
        float s1 = v.x * w[0][1] + v.y * w[1][1] + v.z * w[2][1] + v.w * w[3][1];
        float s2 = v.x * w[0][2] + v.y * w[1][2] + v.z * w[2][2] + v.w * w[3][2];
#pragma unroll
        for (int off = 32; off > 0; off >>= 1) {
            s0 += __shfl_xor(s0, off, 64);
            s1 += __shfl_xor(s1, off, 64);
            s2 += __shfl_xor(s2, off, 64);
        }
        if (lane == 0)
            reinterpret_cast<float4*>(hpre4)[node] = make_float4(s0, s1, s2, 0.f);
    }
}

// ---------- degree pass: degrep[xcd][dst] += 1 ----------
template <bool LOCAL>
__global__ __launch_bounds__(256) void k_deg(const unsigned int* __restrict__ ei,
                                             const int* __restrict__ flag,
                                             float* __restrict__ degrep, int E, int N) {
    const int e = blockIdx.x * 256 + threadIdx.x;
    if (e >= E) return;
    unsigned d;
    if (*flag) d = (unsigned)((const unsigned long long*)ei)[(size_t)E + e];
    else       d = ei[(size_t)E + e];
    if (LOCAL) l2_fadd(degrep + (size_t)xcd_id() * N + d, 1.0f);
    else       atomicAdd(degrep + d, 1.0f);
}

// ---------- reduce deg replicas -> dinv; g = hpre * dinv (in place) ----------
__global__ __launch_bounds__(256) void k_dinv(const float* __restrict__ degrep,
                                              float* __restrict__ dinv,
                                              float* __restrict__ g4,
                                              int nrep, int N) {
    const int i = blockIdx.x * 256 + threadIdx.x;
    if (i >= N) return;
    float s = 1.0f;  // self-loop
    for (int k = 0; k < nrep; ++k) s += degrep[(size_t)k * N + i];
    const float r = rsqrtf(s);
    dinv[i] = r;
    const float4 h = reinterpret_cast<float4*>(g4)[i];
    reinterpret_cast<float4*>(g4)[i] = make_float4(h.x * r, h.y * r, h.z * r, 0.f);
}

// ---------- edge pass: urep[xcd][dst] += g[src]  (3 scalar L2-local atomics) ----
template <bool LOCAL>
__global__ __launch_bounds__(256) void k_edge(const unsigned int* __restrict__ ei,
                                              const int* __restrict__ flag,
                                              const float* __restrict__ g4,
                                              float* __restrict__ urep, int E, int N) {
    const int e = blockIdx.x * 256 + threadIdx.x;
    if (e >= E) return;
    unsigned s, d;
    if (*flag) {
        const unsigned long long* q = (const unsigned long long*)ei;
        s = (unsigned)q[e];
        d = (unsigned)q[(size_t)E + e];
    } else {
        s = ei[e];
        d = ei[(size_t)E + e];
    }
    const float4 gs = reinterpret_cast<const float4*>(g4)[s];
    if (LOCAL) {
        float* base = urep + (((size_t)xcd_id() * N + d) << 2);
        l2_fadd(base + 0, gs.x);
        l2_fadd(base + 1, gs.y);
        l2_fadd(base + 2, gs.z);
    } else {
        float* base = urep + ((size_t)d << 2);
        atomicAdd(base + 0, gs.x);
        atomicAdd(base + 1, gs.y);
        atomicAdd(base + 2, gs.z);
    }
}

// ---------- epilogue: reduce u replicas, relu(+b1) -> h; z = h@W2+b2 ----------
__global__ __launch_bounds__(256) void k_final(const float* __restrict__ urep,
                                               const float* __restrict__ g4,
                                               const float* __restrict__ dinv,
                                               const float* __restrict__ b1,
                                               const float* __restrict__ W2,
                                               const float* __restrict__ b2,
                                               float* __restrict__ out,
                                               int nrep, int N) {
    const int i = blockIdx.x * 256 + threadIdx.x;
    if (i >= N) return;
    float a0 = 0.f, a1 = 0.f, a2 = 0.f;
    for (int k = 0; k < nrep; ++k) {
        const float4 u = reinterpret_cast<const float4*>(urep)[(size_t)k * N + i];
        a0 += u.x; a1 += u.y; a2 += u.z;
    }
    const float r = dinv[i];
    const float4 gg = reinterpret_cast<const float4*>(g4)[i];
    const float h0 = fmaxf(r * (a0 + gg.x) + b1[0], 0.f);
    const float h1 = fmaxf(r * (a1 + gg.y) + b1[1], 0.f);
    const float h2 = fmaxf(r * (a2 + gg.z) + b1[2], 0.f);
    out[3 * (size_t)i + 0] = h0;
    out[3 * (size_t)i + 1] = h1;
    out[3 * (size_t)i + 2] = h2;
    float* z = out + (size_t)3 * N;
#pragma unroll
    for (int c = 0; c < 7; ++c)
        z[7 * (size_t)i + c] = h0 * W2[c] + h1 * W2[7 + c] + h2 * W2[14 + c] + b2[c];
}

extern "C" void kernel_launch(void* const* d_in, const int* in_sizes, int n_in,
                              void* d_out, int out_size, void* d_ws, size_t ws_size,
                              hipStream_t stream) {
    const float*        x   = (const float*)d_in[0];
    const unsigned int* ei  = (const unsigned int*)d_in[1];
    const float*        W1  = (const float*)d_in[2];
    const float*        b1  = (const float*)d_in[3];
    const float*        W2  = (const float*)d_in[4];
    const float*        b2  = (const float*)d_in[5];
    float*              out = (float*)d_out;

    const int N = in_sizes[0] / 256;   // 100000
    const int E = in_sizes[1] / 2;     // 3200000

    // workspace layout (bytes):
    //   [0,256)            flag
    //   g4     : 16N       (hpre, then g = hpre*dinv, stride-4 float)
    //   dinv   : 4N
    //   degrep : 4N*nrep   } contiguous -> zeroed together
    //   urep   : 16N*nrep  }
    const size_t need_main = 256 + (size_t)16 * N + (size_t)4 * N +
                             (size_t)(4 + 16) * N * NXCD;
    const bool   local = (ws_size >= need_main);
    const int    nrep  = local ? NXCD : 1;

    char*  ws     = (char*)d_ws;
    int*   flag   = (int*)ws;
    float* g4     = (float*)(ws + 256);
    float* dinv   = g4 + (size_t)4 * N;
    float* degrep = dinv + N;
    float* urep   = degrep + (size_t)N * nrep;
    const int nzero4 = (int)(((size_t)(4 + 16) * N * nrep) / 16);  // float4 count

    k_detect<<<1, 64, 0, stream>>>(ei, flag);
    k_xw1<<<4096, 256, 0, stream>>>(x, W1, g4, degrep, nzero4, N);
    if (local) {
        k_deg<true><<<(E + 255) / 256, 256, 0, stream>>>(ei, flag, degrep, E, N);
        k_dinv<<<(N + 255) / 256, 256, 0, stream>>>(degrep, dinv, g4, nrep, N);
        k_edge<true><<<(E + 255) / 256, 256, 0, stream>>>(ei, flag, g4, urep, E, N);
    } else {
        k_deg<false><<<(E + 255) / 256, 256, 0, stream>>>(ei, flag, degrep, E, N);
        k_dinv<<<(N + 255) / 256, 256, 0, stream>>>(degrep, dinv, g4, nrep, N);
        k_edge<false><<<(E + 255) / 256, 256, 0, stream>>>(ei, flag, g4, urep, E, N);
    }
    k_final<<<(N + 255) / 256, 256, 0, stream>>>(urep, g4, dinv, b1, W2, b2, out, nrep, N);
}

// Round 4
// 142.478 us; speedup vs baseline: 4.7357x; 4.6826x over previous
//
#include <hip/hip_runtime.h>
#include <stdint.h>

// GCN: h = relu( D^-1/2 (A+I) D^-1/2 (x@W1) + b1 ); z = h@W2 + b2
// out = [h (N*3) | z (N*7)] float32.
//
// Round-4 design: global f32 atomics on gfx950 execute memory-side (~20 G/s,
// 32 B RMW each — measured 307 MB WRITE_SIZE for 9.6M atomics, 471 us). So we
// eliminate per-edge global atomics entirely:
//   1. bin edges by dst into 256-node buckets (4 B records, slot reservation
//      via per-block LDS counting + ONE global atomic per (block,bucket)),
//   2. one block per bucket accumulates degree / messages in LDS (fast ds_add),
//   3. epilogue fully fused into the message kernel.
// Normalization factored: agg[d] = dinv[d]*( sum_{s->d} h[s]*dinv[s] + h[d]*dinv[d] ).

#define BSHIFT 8
#define BNODES 256  // nodes per bucket

// ---------- runtime dtype detection for edge_index (int64 vs int32) ----------
__global__ void k_detect(const unsigned* __restrict__ ei, int* __restrict__ flag) {
    if (blockIdx.x == 0 && threadIdx.x == 0) {
        int is64 = 1;
        for (int i = 1; i < 512; i += 2)
            if (ei[i] != 0u) { is64 = 0; break; }
        *flag = is64;
    }
}

// ---------- h_pre = x @ W1 (stride-4 padded) + zero a small region ----------
__global__ __launch_bounds__(256) void k_xw1(const float* __restrict__ x,
                                             const float* __restrict__ W1,
                                             float* __restrict__ hpre4,
                                             unsigned* __restrict__ zptr,
                                             int nzero_words, int N) {
    const int gtid    = blockIdx.x * 256 + threadIdx.x;
    const int nthread = gridDim.x * 256;
    for (int i = gtid; i < nzero_words; i += nthread) zptr[i] = 0u;

    const int lane = threadIdx.x & 63;
    float w[4][3];
#pragma unroll
    for (int k = 0; k < 4; ++k)
#pragma unroll
        for (int c = 0; c < 3; ++c)
            w[k][c] = W1[(lane * 4 + k) * 3 + c];

    const int wave   = gtid >> 6;
    const int nwaves = nthread >> 6;
    for (int node = wave; node < N; node += nwaves) {
        const float4 v = *reinterpret_cast<const float4*>(x + (size_t)node * 256 + lane * 4);
        float s0 = v.x * w[0][0] + v.y * w[1][0] + v.z * w[2][0] + v.w * w[3][0];
        float s1 = v.x * w[0][1] + v.y * w[1][1] + v.z * w[2][1] + v.w * w[3][1];
        float s2 = v.x * w[0][2] + v.y * w[1][2] + v.z * w[2][2] + v.w * w[3][2];
#pragma unroll
        for (int off = 32; off > 0; off >>= 1) {
            s0 += __shfl_xor(s0, off, 64);
            s1 += __shfl_xor(s1, off, 64);
            s2 += __shfl_xor(s2, off, 64);
        }
        if (lane == 0)
            reinterpret_cast<float4*>(hpre4)[node] = make_float4(s0, s1, s2, 0.f);
    }
}

// ---------- bin edges by dst bucket into 4B records ----------
__global__ __launch_bounds__(512) void k_bin(const unsigned* __restrict__ ei,
                                             const int* __restrict__ flag,
                                             unsigned* __restrict__ gcount,
                                             unsigned* __restrict__ records,
                                             unsigned* __restrict__ ovf_cnt,
                                             unsigned* __restrict__ ovf,
                                             int E, int B, int CAP, int OVFCAP, int CH) {
    __shared__ unsigned cnt[512], base[512], cursor[512];
    const int e0 = blockIdx.x * CH;
    const int e1 = min(E, e0 + CH);
    for (int i = threadIdx.x; i < B; i += 512) { cnt[i] = 0u; cursor[i] = 0u; }
    __syncthreads();
    const bool is64 = (*flag != 0);
    const unsigned long long* e64 = (const unsigned long long*)ei;
    for (int e = e0 + threadIdx.x; e < e1; e += 512) {
        const unsigned d = is64 ? (unsigned)e64[(size_t)E + e] : ei[(size_t)E + e];
        atomicAdd(&cnt[d >> BSHIFT], 1u);
    }
    __syncthreads();
    for (int i = threadIdx.x; i < B; i += 512)
        base[i] = cnt[i] ? atomicAdd(&gcount[i], cnt[i]) : 0u;
    __syncthreads();
    for (int e = e0 + threadIdx.x; e < e1; e += 512) {
        unsigned s, d;
        if (is64) {
            s = (unsigned)e64[e];
            d = (unsigned)e64[(size_t)E + e];
        } else {
            s = ei[e];
            d = ei[(size_t)E + e];
        }
        const unsigned bb  = d >> BSHIFT;
        const unsigned idx = base[bb] + atomicAdd(&cursor[bb], 1u);
        if (idx < (unsigned)CAP) {
            records[(size_t)bb * CAP + idx] = (s << BSHIFT) | (d & (BNODES - 1));
        } else {
            const unsigned o = atomicAdd(ovf_cnt, 1u);
            if (o < (unsigned)OVFCAP) { ovf[2 * o] = s; ovf[2 * o + 1] = d; }
        }
    }
}

// ---------- per-bucket degree count -> g4 = {h*dinv, dinv} ----------
__global__ __launch_bounds__(256) void k_count(const unsigned* __restrict__ gcount,
                                               const unsigned* __restrict__ records,
                                               const unsigned* __restrict__ ovf_cnt,
                                               const unsigned* __restrict__ ovf,
                                               float* __restrict__ g4,
                                               int N, int CAP, int OVFCAP) {
    __shared__ unsigned cnt[BNODES];
    const int b = blockIdx.x;
    cnt[threadIdx.x] = 0u;
    __syncthreads();
    const unsigned n = min(gcount[b], (unsigned)CAP);
    const unsigned* rec = records + (size_t)b * CAP;
    for (unsigned i = threadIdx.x; i < n; i += 256)
        atomicAdd(&cnt[rec[i] & (BNODES - 1)], 1u);
    const unsigned no = min(*ovf_cnt, (unsigned)OVFCAP);
    for (unsigned i = threadIdx.x; i < no; i += 256) {
        const unsigned d = ovf[2 * i + 1];
        if ((int)(d >> BSHIFT) == b) atomicAdd(&cnt[d & (BNODES - 1)], 1u);
    }
    __syncthreads();
    const int node = (b << BSHIFT) + threadIdx.x;
    if (node < N) {
        const float r = rsqrtf(1.0f + (float)cnt[threadIdx.x]);  // +1 self-loop
        const float4 h = reinterpret_cast<const float4*>(g4)[node];
        reinterpret_cast<float4*>(g4)[node] = make_float4(h.x * r, h.y * r, h.z * r, r);
    }
}

// ---------- per-bucket message accumulate + fused epilogue ----------
__global__ __launch_bounds__(256) void k_msg(const unsigned* __restrict__ gcount,
                                             const unsigned* __restrict__ records,
                                             const unsigned* __restrict__ ovf_cnt,
                                             const unsigned* __restrict__ ovf,
                                             const float* __restrict__ g4,
                                             const float* __restrict__ b1,
                                             const float* __restrict__ W2,
                                             const float* __restrict__ b2,
                                             float* __restrict__ out,
                                             int N, int CAP, int OVFCAP) {
    __shared__ float acc[BNODES * 3];
    const int b = blockIdx.x;
    for (int i = threadIdx.x; i < BNODES * 3; i += 256) acc[i] = 0.f;
    __syncthreads();
    const unsigned n = min(gcount[b], (unsigned)CAP);
    const unsigned* rec = records + (size_t)b * CAP;
    for (unsigned i = threadIdx.x; i < n; i += 256) {
        const unsigned r   = rec[i];
        const unsigned low = r & (BNODES - 1);
        const float4   g   = reinterpret_cast<const float4*>(g4)[r >> BSHIFT];
        atomicAdd(&acc[low * 3 + 0], g.x);
        atomicAdd(&acc[low * 3 + 1], g.y);
        atomicAdd(&acc[low * 3 + 2], g.z);
    }
    const unsigned no = min(*ovf_cnt, (unsigned)OVFCAP);
    for (unsigned i = threadIdx.x; i < no; i += 256) {
        const unsigned d = ovf[2 * i + 1];
        if ((int)(d >> BSHIFT) == b) {
            const unsigned low = d & (BNODES - 1);
            const float4   g   = reinterpret_cast<const float4*>(g4)[ovf[2 * i]];
            atomicAdd(&acc[low * 3 + 0], g.x);
            atomicAdd(&acc[low * 3 + 1], g.y);
            atomicAdd(&acc[low * 3 + 2], g.z);
        }
    }
    __syncthreads();
    const int node = (b << BSHIFT) + threadIdx.x;
    if (node < N) {
        const float4 gs = reinterpret_cast<const float4*>(g4)[node];
        const float  r  = gs.w;
        const int    t  = threadIdx.x;
        const float h0 = fmaxf(r * (acc[t * 3 + 0] + gs.x) + b1[0], 0.f);
        const float h1 = fmaxf(r * (acc[t * 3 + 1] + gs.y) + b1[1], 0.f);
        const float h2 = fmaxf(r * (acc[t * 3 + 2] + gs.z) + b1[2], 0.f);
        out[3 * (size_t)node + 0] = h0;
        out[3 * (size_t)node + 1] = h1;
        out[3 * (size_t)node + 2] = h2;
        float* z = out + (size_t)3 * N;
#pragma unroll
        for (int c = 0; c < 7; ++c)
            z[7 * (size_t)node + c] = h0 * W2[c] + h1 * W2[7 + c] + h2 * W2[14 + c] + b2[c];
    }
}

// ================= fallback path (atomic; used only if ws too small) =========
__global__ __launch_bounds__(256) void k_deg_fb(const unsigned* __restrict__ ei,
                                                const int* __restrict__ flag,
                                                float* __restrict__ deg, int E) {
    const int e = blockIdx.x * 256 + threadIdx.x;
    if (e >= E) return;
    const unsigned d = (*flag) ? (unsigned)((const unsigned long long*)ei)[(size_t)E + e]
                               : ei[(size_t)E + e];
    atomicAdd(&deg[d], 1.0f);
}
__global__ __launch_bounds__(256) void k_dinv_fb(const float* __restrict__ deg,
                                                 float* __restrict__ g4, int N) {
    const int i = blockIdx.x * 256 + threadIdx.x;
    if (i >= N) return;
    const float r = rsqrtf(1.0f + deg[i]);
    const float4 h = reinterpret_cast<const float4*>(g4)[i];
    reinterpret_cast<float4*>(g4)[i] = make_float4(h.x * r, h.y * r, h.z * r, r);
}
__global__ __launch_bounds__(256) void k_edge_fb(const unsigned* __restrict__ ei,
                                                 const int* __restrict__ flag,
                                                 const float* __restrict__ g4,
                                                 float* __restrict__ u4, int E) {
    const int e = blockIdx.x * 256 + threadIdx.x;
    if (e >= E) return;
    unsigned s, d;
    if (*flag) {
        const unsigned long long* q = (const unsigned long long*)ei;
        s = (unsigned)q[e];
        d = (unsigned)q[(size_t)E + e];
    } else {
        s = ei[e];
        d = ei[(size_t)E + e];
    }
    const float4 g = reinterpret_cast<const float4*>(g4)[s];
    atomicAdd(&u4[4 * (size_t)d + 0], g.x);
    atomicAdd(&u4[4 * (size_t)d + 1], g.y);
    atomicAdd(&u4[4 * (size_t)d + 2], g.z);
}
__global__ __launch_bounds__(256) void k_final_fb(const float* __restrict__ u4,
                                                  const float* __restrict__ g4,
                                                  const float* __restrict__ b1,
                                                  const float* __restrict__ W2,
                                                  const float* __restrict__ b2,
                                                  float* __restrict__ out, int N) {
    const int i = blockIdx.x * 256 + threadIdx.x;
    if (i >= N) return;
    const float4 gs = reinterpret_cast<const float4*>(g4)[i];
    const float4 u  = reinterpret_cast<const float4*>(u4)[i];
    const float  r  = gs.w;
    const float h0 = fmaxf(r * (u.x + gs.x) + b1[0], 0.f);
    const float h1 = fmaxf(r * (u.y + gs.y) + b1[1], 0.f);
    const float h2 = fmaxf(r * (u.z + gs.z) + b1[2], 0.f);
    out[3 * (size_t)i + 0] = h0;
    out[3 * (size_t)i + 1] = h1;
    out[3 * (size_t)i + 2] = h2;
    float* z = out + (size_t)3 * N;
#pragma unroll
    for (int c = 0; c < 7; ++c)
        z[7 * (size_t)i + c] = h0 * W2[c] + h1 * W2[7 + c] + h2 * W2[14 + c] + b2[c];
}

extern "C" void kernel_launch(void* const* d_in, const int* in_sizes, int n_in,
                              void* d_out, int out_size, void* d_ws, size_t ws_size,
                              hipStream_t stream) {
    const float*    x   = (const float*)d_in[0];
    const unsigned* ei  = (const unsigned*)d_in[1];
    const float*    W1  = (const float*)d_in[2];
    const float*    b1  = (const float*)d_in[3];
    const float*    W2  = (const float*)d_in[4];
    const float*    b2  = (const float*)d_in[5];
    float*          out = (float*)d_out;

    const int N = in_sizes[0] / 256;  // 100000
    const int E = in_sizes[1] / 2;    // 3200000
    const int B = (N + BNODES - 1) >> BSHIFT;  // 391

    // ---- workspace layout (deterministic function of sizes) ----
    char*     ws      = (char*)d_ws;
    int*      flag    = (int*)ws;
    unsigned* gcount  = (unsigned*)(ws + 256);      // B words (also deg area start in fb)
    unsigned* ovf_cnt = gcount + B;                 // 1 word
    size_t    off     = (256 + 4 * (size_t)(B + 1) + 255) & ~(size_t)255;
    float*    g4      = (float*)(ws + off);         // 4N floats {h*dinv, dinv}
    off += 16 * (size_t)N;
    off  = (off + 255) & ~(size_t)255;

    const int OVFCAP = 1 << 16;  // 65536 spill entries (8B each)
    size_t rec_off = off;
    size_t avail   = (ws_size > rec_off + 8 * (size_t)OVFCAP + 4096)
                       ? ws_size - rec_off - 8 * (size_t)OVFCAP - 4096 : 0;
    int CAP = (int)((avail / (4 * (size_t)B)) > 16384 ? 16384 : (avail / (4 * (size_t)B)));
    // mean records/bucket = E/B ~ 8184, sigma ~ 90 -> CAP >= 8960 is +8.6 sigma
    const bool binned = (CAP >= 8960);

    k_detect<<<1, 64, 0, stream>>>(ei, flag);

    if (binned) {
        unsigned* records = (unsigned*)(ws + rec_off);
        unsigned* ovf     = records + (size_t)B * CAP;
        const int CH      = 16384;
        const int nbin    = (E + CH - 1) / CH;
        // zero gcount + ovf_cnt (contiguous B+1 words), fused into k_xw1
        k_xw1<<<4096, 256, 0, stream>>>(x, W1, g4, gcount, B + 1, N);
        k_bin<<<nbin, 512, 0, stream>>>(ei, flag, gcount, records, ovf_cnt, ovf,
                                        E, B, CAP, OVFCAP, CH);
        k_count<<<B, 256, 0, stream>>>(gcount, records, ovf_cnt, ovf, g4, N, CAP, OVFCAP);
        k_msg<<<B, 256, 0, stream>>>(gcount, records, ovf_cnt, ovf, g4,
                                     b1, W2, b2, out, N, CAP, OVFCAP);
    } else {
        // fallback: deg (N floats) + u4 (4N floats) after g4, zeroed in k_xw1
        float* deg = (float*)(ws + rec_off);
        float* u4  = deg + N;
        k_xw1<<<4096, 256, 0, stream>>>(x, W1, g4, (unsigned*)deg, 5 * N, N);
        k_deg_fb<<<(E + 255) / 256, 256, 0, stream>>>(ei, flag, deg, E);
        k_dinv_fb<<<(N + 255) / 256, 256, 0, stream>>>(deg, g4, N);
        k_edge_fb<<<(E + 255) / 256, 256, 0, stream>>>(ei, flag, g4, u4, E);
        k_final_fb<<<(N + 255) / 256, 256, 0, stream>>>(u4, g4, b1, W2, b2, out, N);
    }
}

// Round 5
// 118.385 us; speedup vs baseline: 5.6996x; 1.2035x over previous
//
#include <hip/hip_runtime.h>
#include <stdint.h>

// GCN: h = relu( D^-1/2 (A+I) D^-1/2 (x@W1) + b1 ); z = h@W2 + b2
// out = [h (N*3) | z (N*7)] float32.
//
// Round-5: round-4's bucket binning kept, but the per-bucket count/message
// passes were latency-bound at 12% occupancy (391 blocks, 32 serial
// record->gather round trips per thread, 68 us). Fix:
//   - SPLIT=8 blocks per bucket; LDS partials -> coalesced global partials,
//     reduced by tiny N-thread kernels. 3128 blocks -> ~24 waves/CU.
//   - bin fused into the x@W1 kernel (independent traffic, hides bin latency
//     under the 102 MB streaming read).
//   - int64/int32 edge dtype detected per-block via __syncthreads_or ballot.
// Normalization factored: agg[d] = dinv[d]*( sum_{s->d} h[s]*dinv[s] + h[d]*dinv[d] ).

#define BSHIFT 8
#define BNODES 256
#define OVFCAP 32768

// block-wide int64-vs-int32 ballot: int64 LE => odd 32-bit words of first 256
// entries are all zero (values < 2^17; random int32 ids make this impossible).
// Must be called by ALL threads of the block before any divergence.
__device__ __forceinline__ bool ei_is64(const unsigned* __restrict__ ei) {
    const int t = threadIdx.x;
    const int nz = (t < 256) && (ei[2 * t + 1] != 0u);
    return __syncthreads_or(nz) == 0;
}

// ---------- fused: [bin role | x@W1 role] ----------
__global__ __launch_bounds__(512) void k_pre(const float* __restrict__ x,
                                             const float* __restrict__ W1,
                                             float* __restrict__ g4,
                                             const unsigned* __restrict__ ei,
                                             unsigned* __restrict__ gcount,
                                             unsigned* __restrict__ records,
                                             unsigned* __restrict__ ovf,
                                             int E, int B, int CAP, int CH,
                                             int nbin, int N) {
    const bool is64 = ei_is64(ei);
    if ((int)blockIdx.x < nbin) {
        // ---- bin role: count per bucket, reserve, scatter 4B records ----
        __shared__ unsigned cnt[512], base[512], cursor[512];
        const int e0 = blockIdx.x * CH;
        const int e1 = min(E, e0 + CH);
        for (int i = threadIdx.x; i < B; i += 512) { cnt[i] = 0u; cursor[i] = 0u; }
        __syncthreads();
        const unsigned long long* e64 = (const unsigned long long*)ei;
        for (int e = e0 + threadIdx.x; e < e1; e += 512) {
            const unsigned d = is64 ? (unsigned)e64[(size_t)E + e] : ei[(size_t)E + e];
            atomicAdd(&cnt[d >> BSHIFT], 1u);
        }
        __syncthreads();
        for (int i = threadIdx.x; i < B; i += 512)
            base[i] = cnt[i] ? atomicAdd(&gcount[i], cnt[i]) : 0u;
        __syncthreads();
        unsigned* ovf_cnt = gcount + B;
        for (int e = e0 + threadIdx.x; e < e1; e += 512) {
            unsigned s, d;
            if (is64) { s = (unsigned)e64[e]; d = (unsigned)e64[(size_t)E + e]; }
            else      { s = ei[e];            d = ei[(size_t)E + e]; }
            const unsigned bb  = d >> BSHIFT;
            const unsigned idx = base[bb] + atomicAdd(&cursor[bb], 1u);
            if (idx < (unsigned)CAP) {
                records[(size_t)bb * CAP + idx] = (s << BSHIFT) | (d & (BNODES - 1));
            } else {
                const unsigned o = atomicAdd(ovf_cnt, 1u);
                if (o < (unsigned)OVFCAP) { ovf[2 * o] = s; ovf[2 * o + 1] = d; }
            }
        }
    } else {
        // ---- x@W1 role: one wave per node, 64 lanes x float4 = 256 feats ----
        const int bx      = blockIdx.x - nbin;
        const int gtid    = bx * 512 + threadIdx.x;
        const int nthread = ((int)gridDim.x - nbin) * 512;
        const int lane    = threadIdx.x & 63;
        float w[4][3];
#pragma unroll
        for (int k = 0; k < 4; ++k)
#pragma unroll
            for (int c = 0; c < 3; ++c)
                w[k][c] = W1[(lane * 4 + k) * 3 + c];
        const int wave   = gtid >> 6;
        const int nwaves = nthread >> 6;
        for (int node = wave; node < N; node += nwaves) {
            const float4 v = *reinterpret_cast<const float4*>(x + (size_t)node * 256 + lane * 4);
            float s0 = v.x * w[0][0] + v.y * w[1][0] + v.z * w[2][0] + v.w * w[3][0];
            float s1 = v.x * w[0][1] + v.y * w[1][1] + v.z * w[2][1] + v.w * w[3][1];
            float s2 = v.x * w[0][2] + v.y * w[1][2] + v.z * w[2][2] + v.w * w[3][2];
#pragma unroll
            for (int off = 32; off > 0; off >>= 1) {
                s0 += __shfl_xor(s0, off, 64);
                s1 += __shfl_xor(s1, off, 64);
                s2 += __shfl_xor(s2, off, 64);
            }
            if (lane == 0)
                reinterpret_cast<float4*>(g4)[node] = make_float4(s0, s1, s2, 0.f);
        }
    }
}

// ---------- per-(bucket,slice) degree histogram -> coalesced u32 partials ----
__global__ __launch_bounds__(256) void k_cnt2(const unsigned* __restrict__ gcount,
                                              const unsigned* __restrict__ records,
                                              const unsigned* __restrict__ ovf,
                                              unsigned* __restrict__ pcount,
                                              int B, int CAP, int SPLIT) {
    __shared__ unsigned cnt[BNODES];
    const int b  = blockIdx.x / SPLIT;
    const int sl = blockIdx.x - b * SPLIT;
    cnt[threadIdx.x] = 0u;
    __syncthreads();
    unsigned n = gcount[b]; if (n > (unsigned)CAP) n = CAP;
    const unsigned chunk = (n + SPLIT - 1) / SPLIT;
    const unsigned lo = sl * chunk;
    const unsigned hi = (lo + chunk < n) ? lo + chunk : n;
    const unsigned* rec = records + (size_t)b * CAP;
    for (unsigned i = lo + threadIdx.x; i < hi; i += 256)
        atomicAdd(&cnt[rec[i] & (BNODES - 1)], 1u);
    if (sl == 0) {
        unsigned no = gcount[B]; if (no > (unsigned)OVFCAP) no = OVFCAP;
        for (unsigned i = threadIdx.x; i < no; i += 256) {
            const unsigned d = ovf[2 * i + 1];
            if ((int)(d >> BSHIFT) == b) atomicAdd(&cnt[d & (BNODES - 1)], 1u);
        }
    }
    __syncthreads();
    pcount[((size_t)blockIdx.x << BSHIFT) + threadIdx.x] = cnt[threadIdx.x];
}

// ---------- reduce count partials -> dinv; g4 = {h*dinv, dinv} ----------
__global__ __launch_bounds__(256) void k_dinv2(const unsigned* __restrict__ pcount,
                                               float* __restrict__ g4, int N, int SPLIT) {
    const int i = blockIdx.x * 256 + threadIdx.x;
    if (i >= N) return;
    const int b = i >> BSHIFT, t = i & (BNODES - 1);
    unsigned deg = 1u;  // self-loop
    for (int s = 0; s < SPLIT; ++s)
        deg += pcount[(((size_t)b * SPLIT + s) << BSHIFT) + t];
    const float r = rsqrtf((float)deg);
    const float4 h = reinterpret_cast<const float4*>(g4)[i];
    reinterpret_cast<float4*>(g4)[i] = make_float4(h.x * r, h.y * r, h.z * r, r);
}

// ---------- per-(bucket,slice) message accumulate -> coalesced f32 partials ----
__global__ __launch_bounds__(256) void k_msg2(const unsigned* __restrict__ gcount,
                                              const unsigned* __restrict__ records,
                                              const unsigned* __restrict__ ovf,
                                              const float* __restrict__ g4,
                                              float* __restrict__ psum,
                                              int B, int CAP, int SPLIT) {
    __shared__ float acc[BNODES * 3];
    const int b  = blockIdx.x / SPLIT;
    const int sl = blockIdx.x - b * SPLIT;
    for (int i = threadIdx.x; i < BNODES * 3; i += 256) acc[i] = 0.f;
    __syncthreads();
    unsigned n = gcount[b]; if (n > (unsigned)CAP) n = CAP;
    const unsigned chunk = (n + SPLIT - 1) / SPLIT;
    const unsigned lo = sl * chunk;
    const unsigned hi = (lo + chunk < n) ? lo + chunk : n;
    const unsigned* rec = records + (size_t)b * CAP;
    const float4* g4v = reinterpret_cast<const float4*>(g4);
    unsigned i = lo + threadIdx.x;
    for (; i + 256 < hi; i += 512) {  // 2x ILP: two independent gathers in flight
        const unsigned r0 = rec[i], r1 = rec[i + 256];
        const float4 ga = g4v[r0 >> BSHIFT];
        const float4 gb = g4v[r1 >> BSHIFT];
        const unsigned l0 = (r0 & (BNODES - 1)) * 3, l1 = (r1 & (BNODES - 1)) * 3;
        atomicAdd(&acc[l0 + 0], ga.x); atomicAdd(&acc[l0 + 1], ga.y); atomicAdd(&acc[l0 + 2], ga.z);
        atomicAdd(&acc[l1 + 0], gb.x); atomicAdd(&acc[l1 + 1], gb.y); atomicAdd(&acc[l1 + 2], gb.z);
    }
    if (i < hi) {
        const unsigned r0 = rec[i];
        const float4 ga = g4v[r0 >> BSHIFT];
        const unsigned l0 = (r0 & (BNODES - 1)) * 3;
        atomicAdd(&acc[l0 + 0], ga.x); atomicAdd(&acc[l0 + 1], ga.y); atomicAdd(&acc[l0 + 2], ga.z);
    }
    if (sl == 0) {
        unsigned no = gcount[B]; if (no > (unsigned)OVFCAP) no = OVFCAP;
        for (unsigned k = threadIdx.x; k < no; k += 256) {
            const unsigned d = ovf[2 * k + 1];
            if ((int)(d >> BSHIFT) == b) {
                const float4 g = g4v[ovf[2 * k]];
                const unsigned l = (d & (BNODES - 1)) * 3;
                atomicAdd(&acc[l + 0], g.x); atomicAdd(&acc[l + 1], g.y); atomicAdd(&acc[l + 2], g.z);
            }
        }
    }
    __syncthreads();
    const size_t base = ((size_t)blockIdx.x * 3) << BSHIFT;  // [slice][c][256] layout
    psum[base +   0 + threadIdx.x] = acc[threadIdx.x * 3 + 0];
    psum[base + 256 + threadIdx.x] = acc[threadIdx.x * 3 + 1];
    psum[base + 512 + threadIdx.x] = acc[threadIdx.x * 3 + 2];
}

// ---------- reduce msg partials + fused epilogue ----------
__global__ __launch_bounds__(256) void k_fin(const float* __restrict__ psum,
                                             const float* __restrict__ g4,
                                             const float* __restrict__ b1,
                                             const float* __restrict__ W2,
                                             const float* __restrict__ b2,
                                             float* __restrict__ out, int N, int SPLIT) {
    const int i = blockIdx.x * 256 + threadIdx.x;
    if (i >= N) return;
    const int b = i >> BSHIFT, t = i & (BNODES - 1);
    float a0 = 0.f, a1 = 0.f, a2 = 0.f;
    for (int s = 0; s < SPLIT; ++s) {
        const size_t base = (((size_t)b * SPLIT + s) * 3) << BSHIFT;
        a0 += psum[base + t];
        a1 += psum[base + 256 + t];
        a2 += psum[base + 512 + t];
    }
    const float4 g = reinterpret_cast<const float4*>(g4)[i];
    const float  r = g.w;
    const float h0 = fmaxf(r * (a0 + g.x) + b1[0], 0.f);
    const float h1 = fmaxf(r * (a1 + g.y) + b1[1], 0.f);
    const float h2 = fmaxf(r * (a2 + g.z) + b1[2], 0.f);
    out[3 * (size_t)i + 0] = h0;
    out[3 * (size_t)i + 1] = h1;
    out[3 * (size_t)i + 2] = h2;
    float* z = out + (size_t)3 * N;
#pragma unroll
    for (int c = 0; c < 7; ++c)
        z[7 * (size_t)i + c] = h0 * W2[c] + h1 * W2[7 + c] + h2 * W2[14 + c] + b2[c];
}

// ================= fallback (atomic path; only if ws too small) =============
__global__ __launch_bounds__(256) void k_xw1_fb(const float* __restrict__ x,
                                                const float* __restrict__ W1,
                                                float* __restrict__ g4,
                                                unsigned* __restrict__ zptr,
                                                int nzero, int N) {
    const int gtid = blockIdx.x * 256 + threadIdx.x;
    const int nthread = gridDim.x * 256;
    for (int i = gtid; i < nzero; i += nthread) zptr[i] = 0u;
    const int lane = threadIdx.x & 63;
    float w[4][3];
#pragma unroll
    for (int k = 0; k < 4; ++k)
#pragma unroll
        for (int c = 0; c < 3; ++c) w[k][c] = W1[(lane * 4 + k) * 3 + c];
    const int wave = gtid >> 6, nwaves = nthread >> 6;
    for (int node = wave; node < N; node += nwaves) {
        const float4 v = *reinterpret_cast<const float4*>(x + (size_t)node * 256 + lane * 4);
        float s0 = v.x * w[0][0] + v.y * w[1][0] + v.z * w[2][0] + v.w * w[3][0];
        float s1 = v.x * w[0][1] + v.y * w[1][1] + v.z * w[2][1] + v.w * w[3][1];
        float s2 = v.x * w[0][2] + v.y * w[1][2] + v.z * w[2][2] + v.w * w[3][2];
#pragma unroll
        for (int off = 32; off > 0; off >>= 1) {
            s0 += __shfl_xor(s0, off, 64);
            s1 += __shfl_xor(s1, off, 64);
            s2 += __shfl_xor(s2, off, 64);
        }
        if (lane == 0)
            reinterpret_cast<float4*>(g4)[node] = make_float4(s0, s1, s2, 0.f);
    }
}
__global__ __launch_bounds__(256) void k_deg_fb(const unsigned* __restrict__ ei,
                                                float* __restrict__ deg, int E) {
    const bool is64 = ei_is64(ei);
    const int e = blockIdx.x * 256 + threadIdx.x;
    if (e >= E) return;
    const unsigned d = is64 ? (unsigned)((const unsigned long long*)ei)[(size_t)E + e]
                            : ei[(size_t)E + e];
    atomicAdd(&deg[d], 1.0f);
}
__global__ __launch_bounds__(256) void k_dinv_fb(const float* __restrict__ deg,
                                                 float* __restrict__ g4, int N) {
    const int i = blockIdx.x * 256 + threadIdx.x;
    if (i >= N) return;
    const float r = rsqrtf(1.0f + deg[i]);
    const float4 h = reinterpret_cast<const float4*>(g4)[i];
    reinterpret_cast<float4*>(g4)[i] = make_float4(h.x * r, h.y * r, h.z * r, r);
}
__global__ __launch_bounds__(256) void k_edge_fb(const unsigned* __restrict__ ei,
                                                 const float* __restrict__ g4,
                                                 float* __restrict__ u4, int E) {
    const bool is64 = ei_is64(ei);
    const int e = blockIdx.x * 256 + threadIdx.x;
    if (e >= E) return;
    unsigned s, d;
    if (is64) {
        const unsigned long long* q = (const unsigned long long*)ei;
        s = (unsigned)q[e]; d = (unsigned)q[(size_t)E + e];
    } else {
        s = ei[e]; d = ei[(size_t)E + e];
    }
    const float4 g = reinterpret_cast<const float4*>(g4)[s];
    atomicAdd(&u4[4 * (size_t)d + 0], g.x);
    atomicAdd(&u4[4 * (size_t)d + 1], g.y);
    atomicAdd(&u4[4 * (size_t)d + 2], g.z);
}
__global__ __launch_bounds__(256) void k_final_fb(const float* __restrict__ u4,
                                                  const float* __restrict__ g4,
                                                  const float* __restrict__ b1,
                                                  const float* __restrict__ W2,
                                                  const float* __restrict__ b2,
                                                  float* __restrict__ out, int N) {
    const int i = blockIdx.x * 256 + threadIdx.x;
    if (i >= N) return;
    const float4 g = reinterpret_cast<const float4*>(g4)[i];
    const float4 u = reinterpret_cast<const float4*>(u4)[i];
    const float  r = g.w;
    const float h0 = fmaxf(r * (u.x + g.x) + b1[0], 0.f);
    const float h1 = fmaxf(r * (u.y + g.y) + b1[1], 0.f);
    const float h2 = fmaxf(r * (u.z + g.z) + b1[2], 0.f);
    out[3 * (size_t)i + 0] = h0;
    out[3 * (size_t)i + 1] = h1;
    out[3 * (size_t)i + 2] = h2;
    float* z = out + (size_t)3 * N;
#pragma unroll
    for (int c = 0; c < 7; ++c)
        z[7 * (size_t)i + c] = h0 * W2[c] + h1 * W2[7 + c] + h2 * W2[14 + c] + b2[c];
}

extern "C" void kernel_launch(void* const* d_in, const int* in_sizes, int n_in,
                              void* d_out, int out_size, void* d_ws, size_t ws_size,
                              hipStream_t stream) {
    const float*    x   = (const float*)d_in[0];
    const unsigned* ei  = (const unsigned*)d_in[1];
    const float*    W1  = (const float*)d_in[2];
    const float*    b1  = (const float*)d_in[3];
    const float*    W2  = (const float*)d_in[4];
    const float*    b2  = (const float*)d_in[5];
    float*          out = (float*)d_out;

    const int N = in_sizes[0] / 256;          // 100000
    const int E = in_sizes[1] / 2;            // 3200000
    const int B = (N + BNODES - 1) >> BSHIFT; // 391

    // ---- workspace layout ----
    char*     ws     = (char*)d_ws;
    unsigned* gcount = (unsigned*)ws;                       // B+1 (last = ovf_cnt)
    size_t off = (4ull * (B + 1) + 255) & ~(size_t)255;
    float*    g4  = (float*)(ws + off);                     // 4N {h*dinv, dinv}
    off = (off + 16ull * N + 255) & ~(size_t)255;
    unsigned* ovf = (unsigned*)(ws + off);                  // 2*OVFCAP
    off = (off + 8ull * OVFCAP + 255) & ~(size_t)255;
    const size_t puoff = off;                               // pcount/psum overlay

    int SPLIT = 0, CAP = 0;
    size_t rec_off = 0;
    const int sps[4] = {8, 4, 2, 1};
    for (int si = 0; si < 4; ++si) {
        const int sp = sps[si];
        const size_t ro = (puoff + 4ull * B * sp * 768 + 255) & ~(size_t)255;
        if (ws_size < ro + 4096) continue;
        long cap = (long)((ws_size - ro) / (4ull * B));
        if (cap > 12288) cap = 12288;
        // mean records/bucket = E/B ~ 8184, sigma ~ 90 -> 8960 is +8.6 sigma
        if (cap >= 8960) { SPLIT = sp; CAP = (int)cap; rec_off = ro; break; }
    }

    if (SPLIT) {
        unsigned* pcount  = (unsigned*)(ws + puoff);
        float*    psum    = (float*)(ws + puoff);           // reuses pcount region
        unsigned* records = (unsigned*)(ws + rec_off);
        hipMemsetAsync(gcount, 0, 4ull * (B + 1), stream);
        const int CH   = 16384;
        const int nbin = (E + CH - 1) / CH;
        const int NBX  = 2048;
        k_pre<<<nbin + NBX, 512, 0, stream>>>(x, W1, g4, ei, gcount, records, ovf,
                                              E, B, CAP, CH, nbin, N);
        k_cnt2<<<B * SPLIT, 256, 0, stream>>>(gcount, records, ovf, pcount, B, CAP, SPLIT);
        k_dinv2<<<(N + 255) / 256, 256, 0, stream>>>(pcount, g4, N, SPLIT);
        k_msg2<<<B * SPLIT, 256, 0, stream>>>(gcount, records, ovf, g4, psum, B, CAP, SPLIT);
        k_fin<<<(N + 255) / 256, 256, 0, stream>>>(psum, g4, b1, W2, b2, out, N, SPLIT);
    } else {
        // fallback: deg (N) + u4 (4N) after the overlay base, zeroed in k_xw1_fb
        float* deg = (float*)(ws + puoff);
        float* u4  = deg + N;
        k_xw1_fb<<<4096, 256, 0, stream>>>(x, W1, g4, (unsigned*)deg, 5 * N, N);
        k_deg_fb<<<(E + 255) / 256, 256, 0, stream>>>(ei, deg, E);
        k_dinv_fb<<<(N + 255) / 256, 256, 0, stream>>>(deg, g4, N);
        k_edge_fb<<<(E + 255) / 256, 256, 0, stream>>>(ei, g4, u4, E);
        k_final_fb<<<(N + 255) / 256, 256, 0, stream>>>(u4, g4, b1, W2, b2, out, N);
    }
}

// Round 6
// 116.480 us; speedup vs baseline: 5.7928x; 1.0164x over previous
//
#include <hip/hip_runtime.h>
#include <stdint.h>

// GCN: h = relu( D^-1/2 (A+I) D^-1/2 (x@W1) + b1 ); z = h@W2 + b2
// out = [h (N*3) | z (N*7)] float32.
//
// Round-6: round-5's fused k_pre was latency-bound (82us, VALU 8.7%, HBM 10%):
// the bin role's 3 serial phases (LDS count, global reserve, scatter) on only
// 196 blocks. Fix: ONE-PASS binning with fixed per-block strips:
//   - block j owns slots [j*64, j*64+64) of every bucket; slot from LDS cursor.
//     No count pass, no reserve atomics. P(strip overflow) ~ 6e-4 -> ~50 edges
//     spill to the exact ovf list.
//   - per-strip valid counts pcnt[bucket][block] mask unwritten slots (no memset).
//   - edge loads vectorized (uint4 / ulonglong2 quads): 4 independent
//     cursor-atomic->store chains per thread.
// Consumers (cnt2/msg2) scan all CAP slots with strip-validity masking,
// SPLIT blocks per bucket (round-5's occupancy fix), partials reduced by tiny
// N-thread kernels. Norm factored: agg[d]=dinv[d]*(sum h[s]dinv[s] + h[d]dinv[d]).

#define BSHIFT 8
#define BNODES 256
#define OVFCAP 8192
#define STRIDE 64    // record slots per (bin-block, bucket) strip
#define PSTRIDE 192  // padded strip-count row length in pcnt (>= nbin)

// block-wide int64-vs-int32 ballot: int64 LE => odd 32-bit words of first 256
// entries are all zero (values < 2^17). Call from ALL threads before divergence.
__device__ __forceinline__ bool ei_is64(const unsigned* __restrict__ ei) {
    const int t = threadIdx.x;
    const int nz = (t < 256) && (ei[2 * t + 1] != 0u);
    return __syncthreads_or(nz) == 0;
}

// ---------- fused: [one-pass bin role | x@W1 role] ----------
__global__ __launch_bounds__(512) void k_pre(const float* __restrict__ x,
                                             const float* __restrict__ W1,
                                             float* __restrict__ g4,
                                             const unsigned* __restrict__ ei,
                                             unsigned* __restrict__ records,
                                             unsigned* __restrict__ pcnt,
                                             unsigned* __restrict__ ovf_cnt,
                                             unsigned* __restrict__ ovf,
                                             int E, int B, int CAP, int CH,
                                             int nbin, int N) {
    const bool is64 = ei_is64(ei);
    if ((int)blockIdx.x < nbin) {
        // ---- bin role: scatter 4B records into this block's fixed strips ----
        __shared__ unsigned cursor[512];
        for (int i = threadIdx.x; i < B; i += 512) cursor[i] = 0u;
        __syncthreads();
        const int e0 = blockIdx.x * CH;
        const int e1 = min(E, e0 + CH);
        const unsigned sbase = blockIdx.x * STRIDE;

        auto emit = [&](unsigned s, unsigned d) {
            const unsigned bb  = d >> BSHIFT;
            const unsigned idx = atomicAdd(&cursor[bb], 1u);
            if (idx < STRIDE) {
                records[(size_t)bb * CAP + sbase + idx] = (s << BSHIFT) | (d & (BNODES - 1));
            } else {
                const unsigned o = atomicAdd(ovf_cnt, 1u);
                if (o < OVFCAP) { ovf[2 * o] = s; ovf[2 * o + 1] = d; }
            }
        };

        const int nq = (e1 - e0) >> 2;  // full quads (e0, e1-e0 are 4-aligned)
        if (is64) {
            const unsigned long long* e64 = (const unsigned long long*)ei;
            const ulonglong2* sp = (const ulonglong2*)(e64 + e0);
            const ulonglong2* dp = (const ulonglong2*)(e64 + (size_t)E + e0);
            for (int q = threadIdx.x; q < nq; q += 512) {
                const ulonglong2 sa = sp[2 * q], sb = sp[2 * q + 1];
                const ulonglong2 da = dp[2 * q], db = dp[2 * q + 1];
                emit((unsigned)sa.x, (unsigned)da.x);
                emit((unsigned)sa.y, (unsigned)da.y);
                emit((unsigned)sb.x, (unsigned)db.x);
                emit((unsigned)sb.y, (unsigned)db.y);
            }
            for (int e = e0 + 4 * nq + threadIdx.x; e < e1; e += 512)
                emit((unsigned)e64[e], (unsigned)e64[(size_t)E + e]);
        } else {
            const uint4* sp = (const uint4*)(ei + e0);
            const uint4* dp = (const uint4*)(ei + (size_t)E + e0);
            for (int q = threadIdx.x; q < nq; q += 512) {
                const uint4 s4 = sp[q], d4 = dp[q];
                emit(s4.x, d4.x);
                emit(s4.y, d4.y);
                emit(s4.z, d4.z);
                emit(s4.w, d4.w);
            }
            for (int e = e0 + 4 * nq + threadIdx.x; e < e1; e += 512)
                emit(ei[e], ei[(size_t)E + e]);
        }
        __syncthreads();
        for (int i = threadIdx.x; i < B; i += 512)
            pcnt[(size_t)i * PSTRIDE + blockIdx.x] = min(cursor[i], (unsigned)STRIDE);
    } else {
        // ---- x@W1 role: one wave per node, 64 lanes x float4 = 256 feats ----
        const int bx      = blockIdx.x - nbin;
        const int gtid    = bx * 512 + threadIdx.x;
        const int nthread = ((int)gridDim.x - nbin) * 512;
        const int lane    = threadIdx.x & 63;
        float w[4][3];
#pragma unroll
        for (int k = 0; k < 4; ++k)
#pragma unroll
            for (int c = 0; c < 3; ++c)
                w[k][c] = W1[(lane * 4 + k) * 3 + c];
        const int wave   = gtid >> 6;
        const int nwaves = nthread >> 6;
        for (int node = wave; node < N; node += nwaves) {
            const float4 v = *reinterpret_cast<const float4*>(x + (size_t)node * 256 + lane * 4);
            float s0 = v.x * w[0][0] + v.y * w[1][0] + v.z * w[2][0] + v.w * w[3][0];
            float s1 = v.x * w[0][1] + v.y * w[1][1] + v.z * w[2][1] + v.w * w[3][1];
            float s2 = v.x * w[0][2] + v.y * w[1][2] + v.z * w[2][2] + v.w * w[3][2];
#pragma unroll
            for (int off = 32; off > 0; off >>= 1) {
                s0 += __shfl_xor(s0, off, 64);
                s1 += __shfl_xor(s1, off, 64);
                s2 += __shfl_xor(s2, off, 64);
            }
            if (lane == 0)
                reinterpret_cast<float4*>(g4)[node] = make_float4(s0, s1, s2, 0.f);
        }
    }
}

// ---------- per-(bucket,slice) degree histogram -> coalesced u32 partials ----
__global__ __launch_bounds__(256) void k_cnt2(const unsigned* __restrict__ records,
                                              const unsigned* __restrict__ pcnt,
                                              const unsigned* __restrict__ ovf_cnt,
                                              const unsigned* __restrict__ ovf,
                                              unsigned* __restrict__ pcount,
                                              int B, int CAP, int SPLIT, int nbin) {
    __shared__ unsigned cnt[BNODES];
    __shared__ unsigned scnt[PSTRIDE];
    const int b  = blockIdx.x / SPLIT;
    const int sl = blockIdx.x - b * SPLIT;
    cnt[threadIdx.x] = 0u;
    for (int i = threadIdx.x; i < nbin; i += 256) scnt[i] = pcnt[(size_t)b * PSTRIDE + i];
    __syncthreads();
    const int per = CAP / SPLIT;
    const int lo = sl * per, hi = lo + per;
    const unsigned* rec = records + (size_t)b * CAP;
    for (int k = lo + threadIdx.x; k < hi; k += 256) {
        if ((unsigned)(k & (STRIDE - 1)) < scnt[k >> 6])
            atomicAdd(&cnt[rec[k] & (BNODES - 1)], 1u);
    }
    if (sl == 0) {
        unsigned no = *ovf_cnt; if (no > OVFCAP) no = OVFCAP;
        for (unsigned i = threadIdx.x; i < no; i += 256) {
            const unsigned d = ovf[2 * i + 1];
            if ((int)(d >> BSHIFT) == b) atomicAdd(&cnt[d & (BNODES - 1)], 1u);
        }
    }
    __syncthreads();
    pcount[((size_t)blockIdx.x << BSHIFT) + threadIdx.x] = cnt[threadIdx.x];
}

// ---------- reduce count partials -> dinv; g4 = {h*dinv, dinv} ----------
__global__ __launch_bounds__(256) void k_dinv2(const unsigned* __restrict__ pcount,
                                               float* __restrict__ g4, int N, int SPLIT) {
    const int i = blockIdx.x * 256 + threadIdx.x;
    if (i >= N) return;
    const int b = i >> BSHIFT, t = i & (BNODES - 1);
    unsigned deg = 1u;  // self-loop
    for (int s = 0; s < SPLIT; ++s)
        deg += pcount[(((size_t)b * SPLIT + s) << BSHIFT) + t];
    const float r = rsqrtf((float)deg);
    const float4 h = reinterpret_cast<const float4*>(g4)[i];
    reinterpret_cast<float4*>(g4)[i] = make_float4(h.x * r, h.y * r, h.z * r, r);
}

// ---------- per-(bucket,slice) message accumulate -> coalesced f32 partials ----
__global__ __launch_bounds__(256) void k_msg2(const unsigned* __restrict__ records,
                                              const unsigned* __restrict__ pcnt,
                                              const unsigned* __restrict__ ovf_cnt,
                                              const unsigned* __restrict__ ovf,
                                              const float* __restrict__ g4,
                                              float* __restrict__ psum,
                                              int B, int CAP, int SPLIT, int nbin) {
    __shared__ float acc[BNODES * 3];
    __shared__ unsigned scnt[PSTRIDE];
    const int b  = blockIdx.x / SPLIT;
    const int sl = blockIdx.x - b * SPLIT;
    for (int i = threadIdx.x; i < BNODES * 3; i += 256) acc[i] = 0.f;
    for (int i = threadIdx.x; i < nbin; i += 256) scnt[i] = pcnt[(size_t)b * PSTRIDE + i];
    __syncthreads();
    const int per = CAP / SPLIT;
    const int lo = sl * per, hi = lo + per;
    const unsigned* rec = records + (size_t)b * CAP;
    const float4* g4v = reinterpret_cast<const float4*>(g4);
    for (int k = lo + threadIdx.x; k < hi; k += 256) {
        if ((unsigned)(k & (STRIDE - 1)) < scnt[k >> 6]) {
            const unsigned r = rec[k];
            const float4 g = g4v[r >> BSHIFT];
            const unsigned l = (r & (BNODES - 1)) * 3;
            atomicAdd(&acc[l + 0], g.x);
            atomicAdd(&acc[l + 1], g.y);
            atomicAdd(&acc[l + 2], g.z);
        }
    }
    if (sl == 0) {
        unsigned no = *ovf_cnt; if (no > OVFCAP) no = OVFCAP;
        for (unsigned i = threadIdx.x; i < no; i += 256) {
            const unsigned d = ovf[2 * i + 1];
            if ((int)(d >> BSHIFT) == b) {
                const float4 g = g4v[ovf[2 * i]];
                const unsigned l = (d & (BNODES - 1)) * 3;
                atomicAdd(&acc[l + 0], g.x);
                atomicAdd(&acc[l + 1], g.y);
                atomicAdd(&acc[l + 2], g.z);
            }
        }
    }
    __syncthreads();
    const size_t base = ((size_t)blockIdx.x * 3) << BSHIFT;  // [slice][c][256]
    psum[base +   0 + threadIdx.x] = acc[threadIdx.x * 3 + 0];
    psum[base + 256 + threadIdx.x] = acc[threadIdx.x * 3 + 1];
    psum[base + 512 + threadIdx.x] = acc[threadIdx.x * 3 + 2];
}

// ---------- reduce msg partials + fused epilogue ----------
__global__ __launch_bounds__(256) void k_fin(const float* __restrict__ psum,
                                             const float* __restrict__ g4,
                                             const float* __restrict__ b1,
                                             const float* __restrict__ W2,
                                             const float* __restrict__ b2,
                                             float* __restrict__ out, int N, int SPLIT) {
    const int i = blockIdx.x * 256 + threadIdx.x;
    if (i >= N) return;
    const int b = i >> BSHIFT, t = i & (BNODES - 1);
    float a0 = 0.f, a1 = 0.f, a2 = 0.f;
    for (int s = 0; s < SPLIT; ++s) {
        const size_t base = (((size_t)b * SPLIT + s) * 3) << BSHIFT;
        a0 += psum[base + t];
        a1 += psum[base + 256 + t];
        a2 += psum[base + 512 + t];
    }
    const float4 g = reinterpret_cast<const float4*>(g4)[i];
    const float  r = g.w;
    const float h0 = fmaxf(r * (a0 + g.x) + b1[0], 0.f);
    const float h1 = fmaxf(r * (a1 + g.y) + b1[1], 0.f);
    const float h2 = fmaxf(r * (a2 + g.z) + b1[2], 0.f);
    out[3 * (size_t)i + 0] = h0;
    out[3 * (size_t)i + 1] = h1;
    out[3 * (size_t)i + 2] = h2;
    float* z = out + (size_t)3 * N;
#pragma unroll
    for (int c = 0; c < 7; ++c)
        z[7 * (size_t)i + c] = h0 * W2[c] + h1 * W2[7 + c] + h2 * W2[14 + c] + b2[c];
}

// ================= fallback (atomic path; only if ws too small) =============
__global__ __launch_bounds__(256) void k_xw1_fb(const float* __restrict__ x,
                                                const float* __restrict__ W1,
                                                float* __restrict__ g4,
                                                unsigned* __restrict__ zptr,
                                                int nzero, int N) {
    const int gtid = blockIdx.x * 256 + threadIdx.x;
    const int nthread = gridDim.x * 256;
    for (int i = gtid; i < nzero; i += nthread) zptr[i] = 0u;
    const int lane = threadIdx.x & 63;
    float w[4][3];
#pragma unroll
    for (int k = 0; k < 4; ++k)
#pragma unroll
        for (int c = 0; c < 3; ++c) w[k][c] = W1[(lane * 4 + k) * 3 + c];
    const int wave = gtid >> 6, nwaves = nthread >> 6;
    for (int node = wave; node < N; node += nwaves) {
        const float4 v = *reinterpret_cast<const float4*>(x + (size_t)node * 256 + lane * 4);
        float s0 = v.x * w[0][0] + v.y * w[1][0] + v.z * w[2][0] + v.w * w[3][0];
        float s1 = v.x * w[0][1] + v.y * w[1][1] + v.z * w[2][1] + v.w * w[3][1];
        float s2 = v.x * w[0][2] + v.y * w[1][2] + v.z * w[2][2] + v.w * w[3][2];
#pragma unroll
        for (int off = 32; off > 0; off >>= 1) {
            s0 += __shfl_xor(s0, off, 64);
            s1 += __shfl_xor(s1, off, 64);
            s2 += __shfl_xor(s2, off, 64);
        }
        if (lane == 0)
            reinterpret_cast<float4*>(g4)[node] = make_float4(s0, s1, s2, 0.f);
    }
}
__global__ __launch_bounds__(256) void k_deg_fb(const unsigned* __restrict__ ei,
                                                float* __restrict__ deg, int E) {
    const bool is64 = ei_is64(ei);
    const int e = blockIdx.x * 256 + threadIdx.x;
    if (e >= E) return;
    const unsigned d = is64 ? (unsigned)((const unsigned long long*)ei)[(size_t)E + e]
                            : ei[(size_t)E + e];
    atomicAdd(&deg[d], 1.0f);
}
__global__ __launch_bounds__(256) void k_dinv_fb(const float* __restrict__ deg,
                                                 float* __restrict__ g4, int N) {
    const int i = blockIdx.x * 256 + threadIdx.x;
    if (i >= N) return;
    const float r = rsqrtf(1.0f + deg[i]);
    const float4 h = reinterpret_cast<const float4*>(g4)[i];
    reinterpret_cast<float4*>(g4)[i] = make_float4(h.x * r, h.y * r, h.z * r, r);
}
__global__ __launch_bounds__(256) void k_edge_fb(const unsigned* __restrict__ ei,
                                                 const float* __restrict__ g4,
                                                 float* __restrict__ u4, int E) {
    const bool is64 = ei_is64(ei);
    const int e = blockIdx.x * 256 + threadIdx.x;
    if (e >= E) return;
    unsigned s, d;
    if (is64) {
        const unsigned long long* q = (const unsigned long long*)ei;
        s = (unsigned)q[e]; d = (unsigned)q[(size_t)E + e];
    } else {
        s = ei[e]; d = ei[(size_t)E + e];
    }
    const float4 g = reinterpret_cast<const float4*>(g4)[s];
    atomicAdd(&u4[4 * (size_t)d + 0], g.x);
    atomicAdd(&u4[4 * (size_t)d + 1], g.y);
    atomicAdd(&u4[4 * (size_t)d + 2], g.z);
}
__global__ __launch_bounds__(256) void k_final_fb(const float* __restrict__ u4,
                                                  const float* __restrict__ g4,
                                                  const float* __restrict__ b1,
                                                  const float* __restrict__ W2,
                                                  const float* __restrict__ b2,
                                                  float* __restrict__ out, int N) {
    const int i = blockIdx.x * 256 + threadIdx.x;
    if (i >= N) return;
    const float4 g = reinterpret_cast<const float4*>(g4)[i];
    const float4 u = reinterpret_cast<const float4*>(u4)[i];
    const float  r = g.w;
    const float h0 = fmaxf(r * (u.x + g.x) + b1[0], 0.f);
    const float h1 = fmaxf(r * (u.y + g.y) + b1[1], 0.f);
    const float h2 = fmaxf(r * (u.z + g.z) + b1[2], 0.f);
    out[3 * (size_t)i + 0] = h0;
    out[3 * (size_t)i + 1] = h1;
    out[3 * (size_t)i + 2] = h2;
    float* z = out + (size_t)3 * N;
#pragma unroll
    for (int c = 0; c < 7; ++c)
        z[7 * (size_t)i + c] = h0 * W2[c] + h1 * W2[7 + c] + h2 * W2[14 + c] + b2[c];
}

extern "C" void kernel_launch(void* const* d_in, const int* in_sizes, int n_in,
                              void* d_out, int out_size, void* d_ws, size_t ws_size,
                              hipStream_t stream) {
    const float*    x   = (const float*)d_in[0];
    const unsigned* ei  = (const unsigned*)d_in[1];
    const float*    W1  = (const float*)d_in[2];
    const float*    b1  = (const float*)d_in[3];
    const float*    W2  = (const float*)d_in[4];
    const float*    b2  = (const float*)d_in[5];
    float*          out = (float*)d_out;

    const int N = in_sizes[0] / 256;          // 100000
    const int E = in_sizes[1] / 2;            // 3200000
    const int B = (N + BNODES - 1) >> BSHIFT; // 391

    // bin geometry: <=190 blocks, chunk multiple of 4 for vector loads
    int CH   = ((E + 189) / 190 + 3) & ~3;
    int nbin = (E + CH - 1) / CH;             // <= 190 (fits PSTRIDE=192)
    int CAP  = nbin * STRIDE;                 // total slots per bucket

    // ---- workspace layout ----
    char*     ws      = (char*)d_ws;
    unsigned* ovf_cnt = (unsigned*)ws;                       // 1 word
    size_t off = 256;
    float*    g4  = (float*)(ws + off);                      // 4N {h*dinv, dinv}
    off = (off + 16ull * N + 255) & ~(size_t)255;
    unsigned* ovf = (unsigned*)(ws + off);                   // 2*OVFCAP
    off = (off + 8ull * OVFCAP + 255) & ~(size_t)255;
    unsigned* pcnt = (unsigned*)(ws + off);                  // B*PSTRIDE strip counts
    off = (off + 4ull * B * PSTRIDE + 255) & ~(size_t)255;
    const size_t puoff = off;                                // pcount/psum overlay

    int SPLIT = 0;
    size_t rec_off = 0;
    const int sps[4] = {8, 4, 2, 1};
    for (int si = 0; si < 4; ++si) {
        const int sp = sps[si];
        const size_t ro = (puoff + 4ull * B * sp * 768 + 255) & ~(size_t)255;
        if (ws_size >= ro + 4ull * B * CAP + 4096) { SPLIT = sp; rec_off = ro; break; }
    }

    if (SPLIT) {
        unsigned* pcount  = (unsigned*)(ws + puoff);
        float*    psum    = (float*)(ws + puoff);            // overlay
        unsigned* records = (unsigned*)(ws + rec_off);
        hipMemsetAsync(ovf_cnt, 0, 4, stream);
        const int NBX = 2048;
        k_pre<<<nbin + NBX, 512, 0, stream>>>(x, W1, g4, ei, records, pcnt,
                                              ovf_cnt, ovf, E, B, CAP, CH, nbin, N);
        k_cnt2<<<B * SPLIT, 256, 0, stream>>>(records, pcnt, ovf_cnt, ovf, pcount,
                                              B, CAP, SPLIT, nbin);
        k_dinv2<<<(N + 255) / 256, 256, 0, stream>>>(pcount, g4, N, SPLIT);
        k_msg2<<<B * SPLIT, 256, 0, stream>>>(records, pcnt, ovf_cnt, ovf, g4, psum,
                                              B, CAP, SPLIT, nbin);
        k_fin<<<(N + 255) / 256, 256, 0, stream>>>(psum, g4, b1, W2, b2, out, N, SPLIT);
    } else {
        // fallback: deg (N) + u4 (4N) after overlay base, zeroed in k_xw1_fb
        float* deg = (float*)(ws + puoff);
        float* u4  = deg + N;
        k_xw1_fb<<<4096, 256, 0, stream>>>(x, W1, g4, (unsigned*)deg, 5 * N, N);
        k_deg_fb<<<(E + 255) / 256, 256, 0, stream>>>(ei, deg, E);
        k_dinv_fb<<<(N + 255) / 256, 256, 0, stream>>>(deg, g4, N);
        k_edge_fb<<<(E + 255) / 256, 256, 0, stream>>>(ei, g4, u4, E);
        k_final_fb<<<(N + 255) / 256, 256, 0, stream>>>(u4, g4, b1, W2, b2, out, N);
    }
}